// Round 2
// baseline (624.949 us; speedup 1.0000x reference)
//
#include <hip/hip_runtime.h>
#include <math.h>

#define BATCH 16384
#define LATENT 16

// ---------------------------------------------------------------------------
// FFM forward:
//   fm[b]  = sum_{i<j} dot( mean_s E_i[j-1][x_i[b,s]], mean_s E_j[i][x_j[b,s]] )
//   lin[b] = relu( sum_i mean_s(L_i[x_i[b,s]]) * Wd[i] + bd )
//   out[b] = sigmoid(lin[b] + fm[b])
//
// Layout: 16 lanes per batch element, lane = latent dim. Each E-row read is a
// coalesced 64B transaction. 30 per-lane accumulators (6 fields x 5 slots).
//
// NOTE input order: setup_inputs() dict order is x0..x5, then (E_i, L_i)
// INTERLEAVED per field, then Wd, bd. kernel_launch verifies via in_sizes.
// ---------------------------------------------------------------------------

template<int SEQ, int DIM>
__device__ __forceinline__ void field_accum(const int* __restrict__ x,
                                            const float* __restrict__ E,
                                            const float* __restrict__ L,
                                            int b, int t,
                                            float v[5], float& lmean)
{
    const size_t slotStride = (size_t)DIM * LATENT;
    float a0 = 0.f, a1 = 0.f, a2 = 0.f, a3 = 0.f, a4 = 0.f, ls = 0.f;
#pragma unroll 2
    for (int s = 0; s < SEQ; ++s) {
        const int idx = x[b * SEQ + s];
        const size_t off = (size_t)idx * LATENT + t;
        a0 += E[off];
        a1 += E[off + slotStride];
        a2 += E[off + 2 * slotStride];
        a3 += E[off + 3 * slotStride];
        a4 += E[off + 4 * slotStride];
        ls += L[idx];   // same-address within 16-lane group -> broadcast
    }
    const float inv = 1.0f / (float)SEQ;
    v[0] = a0 * inv; v[1] = a1 * inv; v[2] = a2 * inv;
    v[3] = a3 * inv; v[4] = a4 * inv;
    lmean = ls * inv;
}

__global__ __launch_bounds__(256) void ffm_kernel(
    const int* __restrict__ x0, const int* __restrict__ x1,
    const int* __restrict__ x2, const int* __restrict__ x3,
    const int* __restrict__ x4, const int* __restrict__ x5,
    const float* __restrict__ E0, const float* __restrict__ E1,
    const float* __restrict__ E2, const float* __restrict__ E3,
    const float* __restrict__ E4, const float* __restrict__ E5,
    const float* __restrict__ L0, const float* __restrict__ L1,
    const float* __restrict__ L2, const float* __restrict__ L3,
    const float* __restrict__ L4, const float* __restrict__ L5,
    const float* __restrict__ Wd, const float* __restrict__ bd,
    float* __restrict__ out)
{
    const int tid = blockIdx.x * blockDim.x + threadIdx.x;
    const int b = tid >> 4;     // batch element (16 lanes each)
    const int t = tid & 15;     // latent dim

    float v0[5], v1[5], v2[5], v3[5], v4[5], v5[5];
    float f0, f1, f2, f3, f4, f5;

    field_accum<1, 1000000>(x0, E0, L0, b, t, v0, f0);
    field_accum<1,  500000>(x1, E1, L1, b, t, v1, f1);
    field_accum<50, 500000>(x2, E2, L2, b, t, v2, f2);
    field_accum<20, 100000>(x3, E3, L3, b, t, v3, f3);
    field_accum<1,   10000>(x4, E4, L4, b, t, v4, f4);
    field_accum<1,    1000>(x5, E5, L5, b, t, v5, f5);

    // fm partial for this latent dim: pairs (i<j) -> v[i][j-1] * v[j][i]
    float fm = v0[0] * v1[0] + v0[1] * v2[0] + v0[2] * v3[0]
             + v0[3] * v4[0] + v0[4] * v5[0]
             + v1[1] * v2[1] + v1[2] * v3[1] + v1[3] * v4[1] + v1[4] * v5[1]
             + v2[2] * v3[2] + v2[3] * v4[2] + v2[4] * v5[2]
             + v3[3] * v4[3] + v3[4] * v5[3]
             + v4[4] * v5[4];

    // butterfly reduce across the 16-lane group (latent dims)
    fm += __shfl_xor(fm, 1, 16);
    fm += __shfl_xor(fm, 2, 16);
    fm += __shfl_xor(fm, 4, 16);
    fm += __shfl_xor(fm, 8, 16);

    if (t == 0) {
        float lin = f0 * Wd[0] + f1 * Wd[1] + f2 * Wd[2]
                  + f3 * Wd[3] + f4 * Wd[4] + f5 * Wd[5] + bd[0];
        lin = fmaxf(lin, 0.0f);
        const float z = lin + fm;
        out[b] = 1.0f / (1.0f + __expf(-z));
    }
}

extern "C" void kernel_launch(void* const* d_in, const int* in_sizes, int n_in,
                              void* d_out, int out_size, void* d_ws, size_t ws_size,
                              hipStream_t stream)
{
    const int* x0 = (const int*)d_in[0];
    const int* x1 = (const int*)d_in[1];
    const int* x2 = (const int*)d_in[2];
    const int* x3 = (const int*)d_in[3];
    const int* x4 = (const int*)d_in[4];
    const int* x5 = (const int*)d_in[5];

    const float *E0, *E1, *E2, *E3, *E4, *E5;
    const float *L0, *L1, *L2, *L3, *L4, *L5;

    // setup_inputs() dict order interleaves (E_i, L_i). Detect defensively:
    // in_sizes[7] == 1,000,000 -> interleaved (d_in[7] is L0);
    // in_sizes[7] == 40,000,000 -> grouped   (d_in[7] is E1).
    if (in_sizes[7] == 1000000) {
        E0 = (const float*)d_in[6];  L0 = (const float*)d_in[7];
        E1 = (const float*)d_in[8];  L1 = (const float*)d_in[9];
        E2 = (const float*)d_in[10]; L2 = (const float*)d_in[11];
        E3 = (const float*)d_in[12]; L3 = (const float*)d_in[13];
        E4 = (const float*)d_in[14]; L4 = (const float*)d_in[15];
        E5 = (const float*)d_in[16]; L5 = (const float*)d_in[17];
    } else {
        E0 = (const float*)d_in[6];  E1 = (const float*)d_in[7];
        E2 = (const float*)d_in[8];  E3 = (const float*)d_in[9];
        E4 = (const float*)d_in[10]; E5 = (const float*)d_in[11];
        L0 = (const float*)d_in[12]; L1 = (const float*)d_in[13];
        L2 = (const float*)d_in[14]; L3 = (const float*)d_in[15];
        L4 = (const float*)d_in[16]; L5 = (const float*)d_in[17];
    }
    const float* Wd = (const float*)d_in[18];
    const float* bd = (const float*)d_in[19];
    float* out = (float*)d_out;

    dim3 block(256);
    dim3 grid((BATCH * LATENT) / 256);   // 1024 blocks, 16 elements/block
    hipLaunchKernelGGL(ffm_kernel, grid, block, 0, stream,
                       x0, x1, x2, x3, x4, x5,
                       E0, E1, E2, E3, E4, E5,
                       L0, L1, L2, L3, L4, L5,
                       Wd, bd, out);
}